// Round 1
// baseline (425.674 us; speedup 1.0000x reference)
//
#include <hip/hip_runtime.h>
#include <math.h>

#define TPB 512
#define NBINS 512
#define CAP 2048
#define NSEL 64

typedef unsigned long long u64t;

// order-preserving key: descending by value (ascending uint key), ties -> ascending idx
__device__ __forceinline__ unsigned int fkeyDesc(float v) {
  unsigned int b = __float_as_uint(v);
  unsigned int o = (b & 0x80000000u) ? ~b : (b | 0x80000000u);  // ascending order
  return ~o;                                                    // descending
}
__device__ __forceinline__ float fkeyInv(unsigned int kd) {
  unsigned int o = ~kd;
  unsigned int b = (o & 0x80000000u) ? (o & 0x7fffffffu) : ~o;
  return __uint_as_float(b);
}

__device__ void bitonicSortShared(u64t* keys) {
  for (unsigned int k = 2; k <= CAP; k <<= 1) {
    for (unsigned int j = k >> 1; j > 0; j >>= 1) {
      __syncthreads();
      for (unsigned int i = threadIdx.x; i < CAP; i += TPB) {
        unsigned int ixj = i ^ j;
        if (ixj > i) {
          u64t a = keys[i], b = keys[ixj];
          bool up = ((i & k) == 0);
          if ((a > b) == up) { keys[i] = b; keys[ixj] = a; }
        }
      }
    }
  }
  __syncthreads();
}

__global__ __launch_bounds__(TPB) void sampler_kernel(
    const float* __restrict__ logits,
    const float* __restrict__ temp_arr,
    const float* __restrict__ minp_arr,
    const float* __restrict__ topp_arr,
    const int*   __restrict__ topk_arr,
    const float* __restrict__ u_arr,
    float* __restrict__ out,
    int T, int V, int NL)
{
  __shared__ u64t keyA[CAP];
  __shared__ u64t keyB[CAP];
  __shared__ float pvals[CAP];
  __shared__ int   cnthist[NBINS];
  __shared__ u64t  masshist[NBINS];
  __shared__ float sv[TPB];
  __shared__ int   si[TPB];
  __shared__ float  sh_m0, sh_S0, sh_S, sh_Sp, sh_thresh, sh_toklp, sh_Rnext;
  __shared__ double sh_seedD;
  __shared__ int sh_gidx, sh_ck, sh_B64, sh_Bp, sh_cnt, sh_done, sh_sampled, sh_rank;

  const int row = blockIdx.x;
  const int tid = threadIdx.x;
  const float* x  = logits + (size_t)row * V;
  const float* uu = u_arr  + (size_t)row * V;
  const float temp = temp_arr[row];
  const float minp = minp_arr[row];
  const float topp = topp_arr[row];
  const int   topk = topk_arr[row];
  const bool greedy = (temp < 1e-5f);
  const float st = greedy ? 1.0f : temp;   // safe_temp
  const int V4 = V >> 2;
  const float4* x4 = (const float4*)x;

  // ================= P1: max + argmax of raw logits =================
  float lm = -INFINITY; int lidx = 0;
  for (int i4 = tid; i4 < V4; i4 += TPB) {
    float4 v = x4[i4]; int b = i4 << 2;
    if (v.x > lm) { lm = v.x; lidx = b; }
    if (v.y > lm) { lm = v.y; lidx = b + 1; }
    if (v.z > lm) { lm = v.z; lidx = b + 2; }
    if (v.w > lm) { lm = v.w; lidx = b + 3; }
  }
  for (int i = (V4 << 2) + tid; i < V; i += TPB) {
    float v = x[i]; if (v > lm) { lm = v; lidx = i; }
  }
  sv[tid] = lm; si[tid] = lidx; __syncthreads();
  for (int s = TPB / 2; s > 0; s >>= 1) {
    if (tid < s) {
      float v2 = sv[tid + s]; int i2 = si[tid + s];
      if (v2 > sv[tid] || (v2 == sv[tid] && i2 < si[tid])) { sv[tid] = v2; si[tid] = i2; }
    }
    __syncthreads();
  }
  if (tid == 0) { sh_m0 = sv[0]; sh_gidx = si[0]; }
  __syncthreads();
  const float m0 = sh_m0;
  const int gidx = sh_gidx;
  const float ml = m0 / st;   // max of l = x/st (division is monotone)

  // ================= P2: S0 = sum exp(x-m0), S = sum exp(l-ml) ======
  float s0p = 0.f, slp = 0.f;
  for (int i4 = tid; i4 < V4; i4 += TPB) {
    float4 v = x4[i4];
    s0p += expf(v.x - m0) + expf(v.y - m0) + expf(v.z - m0) + expf(v.w - m0);
    slp += expf(v.x / st - ml) + expf(v.y / st - ml) + expf(v.z / st - ml) + expf(v.w / st - ml);
  }
  for (int i = (V4 << 2) + tid; i < V; i += TPB) {
    float v = x[i]; s0p += expf(v - m0); slp += expf(v / st - ml);
  }
  sv[tid] = s0p; __syncthreads();
  for (int s = TPB / 2; s > 0; s >>= 1) { if (tid < s) sv[tid] += sv[tid + s]; __syncthreads(); }
  if (tid == 0) sh_S0 = sv[0];
  __syncthreads();
  sv[tid] = slp; __syncthreads();
  for (int s = TPB / 2; s > 0; s >>= 1) { if (tid < s) sv[tid] += sv[tid + s]; __syncthreads(); }
  if (tid == 0) sh_S = sv[0];
  __syncthreads();
  const float S0 = sh_S0;
  const float S  = sh_S;
  const float logS0 = logf(S0);
  const float rhs = minp * (1.0f / S);    // min_p * max_p, as in reference

  // ===== P3: count hist (top-64 select) + mass hist (top_k==0) + S', cntKeep
  const bool needMass = (!greedy && topk <= 0);
  float Rcur = 8.0f;
  float binScale = (float)NBINS / Rcur;
  float Sp = 0.f; int ck = 0;
  for (int attempt = 0; attempt < 8; ++attempt) {
    binScale = (float)NBINS / Rcur;
    for (int b = tid; b < NBINS; b += TPB) { cnthist[b] = 0; masshist[b] = 0ull; }
    __syncthreads();
    float spp = 0.f; int ckp = 0;
    auto body3 = [&](float vv, int gi) {
      float l = vv / st;
      float e = expf(l - ml);
      bool keep = ((e / S) >= rhs);
      if (keep) { spp += e; ckp++; }
      float fb = (m0 - vv) * binScale;
      if (fb < (float)NBINS) {
        int bin = (int)fb;
        atomicAdd(&cnthist[bin], 1);
        if (keep && needMass)
          atomicAdd(&masshist[bin], (u64t)((double)e * 4294967296.0));  // fixed-point: deterministic
      }
    };
    for (int i4 = tid; i4 < V4; i4 += TPB) {
      float4 v = x4[i4]; int b = i4 << 2;
      body3(v.x, b); body3(v.y, b + 1); body3(v.z, b + 2); body3(v.w, b + 3);
    }
    for (int i = (V4 << 2) + tid; i < V; i += TPB) body3(x[i], i);
    __syncthreads();
    sv[tid] = spp; __syncthreads();
    for (int s = TPB / 2; s > 0; s >>= 1) { if (tid < s) sv[tid] += sv[tid + s]; __syncthreads(); }
    if (tid == 0) sh_Sp = sv[0];
    __syncthreads();
    si[tid] = ckp; __syncthreads();
    for (int s = TPB / 2; s > 0; s >>= 1) { if (tid < s) si[tid] += si[tid + s]; __syncthreads(); }
    if (tid == 0) sh_ck = si[0];
    __syncthreads();
    Sp = sh_Sp; ck = sh_ck;
    if (tid == 0) {
      int need = V < NSEL ? V : NSEL;
      if (topk > need && topk <= CAP / 2) need = topk;
      long long cum = 0; int b64 = -1; long long c64 = 0;
      for (int b = 0; b < NBINS; ++b) {
        cum += cnthist[b];
        if (cum >= need) { b64 = b; c64 = cum; break; }
      }
      int ok = 1;
      if (b64 < 0) ok = 0;            // widen range
      else if (c64 > CAP) ok = 2;     // zoom in
      int bp = -1; double seed = 0.0;
      if (needMass) {
        double TP = (double)topp * (double)Sp;
        double cm = 0.0;
        for (int b = 0; b < NBINS; ++b) {
          if (masshist[b] > 0ull && cm < TP) { bp = b; seed = cm; }
          cm += (double)masshist[b] * (1.0 / 4294967296.0);
        }
        if (cm < TP) ok = 0;          // crossing beyond range -> widen
        if (bp < 0) ok = 0;
      }
      sh_B64 = b64; sh_Bp = bp; sh_seedD = seed;
      sh_done = ok;
      sh_Rnext = (ok == 0) ? Rcur * 4.0f : ((ok == 2) ? Rcur * 0.25f : Rcur);
    }
    __syncthreads();
    if (sh_done == 1) break;
    Rcur = sh_Rnext;
    __syncthreads();
  }
  const int B64 = sh_B64;
  const int Bp  = sh_Bp;

  // ===== P4: collect top candidate bins; sort by x (keyA) and by lp (keyB)
  if (tid == 0) sh_cnt = 0;
  __syncthreads();
  {
    auto body4 = [&](float vv, int gi) {
      float fb = (m0 - vv) * binScale;
      if (fb < (float)NBINS) {
        int bin = (int)fb;
        if (bin <= B64) {
          int pos = atomicAdd(&sh_cnt, 1);
          if (pos < CAP) {
            keyA[pos] = ((u64t)fkeyDesc(vv) << 32) | (unsigned int)gi;
            float lp = (vv - m0) - logS0;
            keyB[pos] = ((u64t)fkeyDesc(lp) << 32) | (unsigned int)gi;
          }
        }
      }
    };
    for (int i4 = tid; i4 < V4; i4 += TPB) {
      float4 v = x4[i4]; int b = i4 << 2;
      body4(v.x, b); body4(v.y, b + 1); body4(v.z, b + 2); body4(v.w, b + 3);
    }
    for (int i = (V4 << 2) + tid; i < V; i += TPB) body4(x[i], i);
  }
  __syncthreads();
  {
    int Cact = sh_cnt; if (Cact > CAP) Cact = CAP;
    for (int i = Cact + tid; i < CAP; i += TPB) { keyA[i] = ~0ull; keyB[i] = ~0ull; }
  }
  __syncthreads();
  bitonicSortShared(keyA);
  bitonicSortShared(keyB);

  // ===== threshold (combined top-k/top-p), only for non-greedy rows =====
  if (!greedy) {
    if (topk > 0) {
      if (tid == 0) {
        int k = topk; if (k > V) k = V; if (k > CAP) k = CAP;
        int jp = 0; float cum = 0.f;
        for (int j = 0; j < k; ++j) {
          float pj = 0.f;
          if (j < ck) {   // kept elements are exactly the top-ck by value (min_p keep is monotone in x)
            float xv = fkeyInv((unsigned int)(keyA[j] >> 32));
            pj = expf(xv / st - ml) / Sp;
          }
          cum += pj;
          float ex = cum - pj;          // emulate ref's (cumsum - probs)
          if (ex < topp) jp = j;
        }
        float thr;
        if (jp < ck) {
          float xv = fkeyInv((unsigned int)(keyA[jp] >> 32));
          thr = xv / st;
        } else thr = -INFINITY;
        sh_thresh = thr;
      }
      __syncthreads();
    } else {
      if (Bp >= 0) {
        // collect the top-p crossing bin (kept elems only), sort, sequential scan
        if (tid == 0) sh_cnt = 0;
        __syncthreads();
        auto body5 = [&](float vv, int gi) {
          float fb = (m0 - vv) * binScale;
          if (fb < (float)NBINS) {
            int bin = (int)fb;
            if (bin == Bp) {
              float l = vv / st;
              float e = expf(l - ml);
              if ((e / S) >= rhs) {
                int pos = atomicAdd(&sh_cnt, 1);
                if (pos < CAP) keyA[pos] = ((u64t)fkeyDesc(vv) << 32) | (unsigned int)gi;
              }
            }
          }
        };
        for (int i4 = tid; i4 < V4; i4 += TPB) {
          float4 v = x4[i4]; int b = i4 << 2;
          body5(v.x, b); body5(v.y, b + 1); body5(v.z, b + 2); body5(v.w, b + 3);
        }
        for (int i = (V4 << 2) + tid; i < V; i += TPB) body5(x[i], i);
        __syncthreads();
        int C5 = sh_cnt; if (C5 > CAP) C5 = CAP;
        for (int i = C5 + tid; i < CAP; i += TPB) keyA[i] = ~0ull;
        __syncthreads();
        bitonicSortShared(keyA);
        for (int j = tid; j < C5; j += TPB) {
          float xv = fkeyInv((unsigned int)(keyA[j] >> 32));
          pvals[j] = expf(xv / st - ml) / Sp;
        }
        __syncthreads();
        if (tid == 0) {
          float cum = (float)(sh_seedD / (double)Sp);   // exclusive mass before this bin
          float lastVal = fkeyInv((unsigned int)(keyA[0] >> 32));
          for (int j = 0; j < C5; ++j) {
            float pj = pvals[j];
            cum += pj;
            float ex = cum - pj;
            if (ex < topp) lastVal = fkeyInv((unsigned int)(keyA[j] >> 32));
          }
          sh_thresh = lastVal / st;
        }
        __syncthreads();
      } else {
        if (tid == 0) sh_thresh = -INFINITY;
        __syncthreads();
      }
    }
  }

  // ===== P6: Gumbel argmax over kept candidates (skip for greedy rows) =====
  if (!greedy) {
    const float thr = sh_thresh;
    const float4* u4 = (const float4*)uu;
    float bm = -INFINITY; int bi = 0x7fffffff;
    auto body6 = [&](float vv, float uv, int gi) {
      float l = vv / st;
      float e = expf(l - ml);
      float val = -INFINITY;
      if (((e / S) >= rhs) && (l >= thr)) {
        float g = -logf(-logf(uv));
        val = l + g;
      }
      if (val > bm || (val == bm && gi < bi)) { bm = val; bi = gi; }
    };
    for (int i4 = tid; i4 < V4; i4 += TPB) {
      float4 v = x4[i4]; float4 w = u4[i4]; int b = i4 << 2;
      body6(v.x, w.x, b); body6(v.y, w.y, b + 1); body6(v.z, w.z, b + 2); body6(v.w, w.w, b + 3);
    }
    for (int i = (V4 << 2) + tid; i < V; i += TPB) body6(x[i], uu[i], i);
    sv[tid] = bm; si[tid] = bi; __syncthreads();
    for (int s = TPB / 2; s > 0; s >>= 1) {
      if (tid < s) {
        float v2 = sv[tid + s]; int i2 = si[tid + s];
        if (v2 > sv[tid] || (v2 == sv[tid] && i2 < si[tid])) { sv[tid] = v2; si[tid] = i2; }
      }
      __syncthreads();
    }
    if (tid == 0) sh_sampled = si[0];
    __syncthreads();
  } else {
    if (tid == 0) sh_sampled = gidx;
    __syncthreads();
  }
  const int sampled = sh_sampled;

  // ===== P7: token logprob + rank =====
  if (tid == 0) sh_toklp = (x[sampled] - m0) - logS0;
  __syncthreads();
  const float toklp = sh_toklp;
  int rc = 0;
  auto body7 = [&](float vv, int gi) {
    float lp = (vv - m0) - logS0;
    if (lp >= toklp) rc++;
  };
  for (int i4 = tid; i4 < V4; i4 += TPB) {
    float4 v = x4[i4]; int b = i4 << 2;
    body7(v.x, b); body7(v.y, b + 1); body7(v.z, b + 2); body7(v.w, b + 3);
  }
  for (int i = (V4 << 2) + tid; i < V; i += TPB) body7(x[i], i);
  si[tid] = rc; __syncthreads();
  for (int s = TPB / 2; s > 0; s >>= 1) { if (tid < s) si[tid] += si[tid + s]; __syncthreads(); }
  if (tid == 0) sh_rank = si[0];
  __syncthreads();

  // ===== P8: outputs (all written as float32 into the concat buffer) =====
  float* o_samp = out;                                   // [T]
  float* o_idx  = out + T;                               // [T, NL+1]
  float* o_lps  = out + T + (size_t)T * (NL + 1);        // [T, NL+1]
  float* o_rank = out + T + (size_t)2 * T * (NL + 1);    // [T]
  if (tid == 0) {
    o_samp[row] = (float)sampled;
    o_idx[(size_t)row * (NL + 1)] = (float)sampled;
    o_lps[(size_t)row * (NL + 1)] = toklp;
    o_rank[row] = (float)sh_rank;
  }
  for (int j = tid; j < NL; j += TPB) {
    u64t kb = keyB[j];
    o_idx[(size_t)row * (NL + 1) + 1 + j] = (float)(unsigned int)(kb & 0xffffffffu);
    o_lps[(size_t)row * (NL + 1) + 1 + j] = fkeyInv((unsigned int)(kb >> 32));
  }
}

extern "C" void kernel_launch(void* const* d_in, const int* in_sizes, int n_in,
                              void* d_out, int out_size, void* d_ws, size_t ws_size,
                              hipStream_t stream) {
  const float* logits = (const float*)d_in[0];
  const float* temp   = (const float*)d_in[1];
  const float* minp   = (const float*)d_in[2];
  const float* topp   = (const float*)d_in[3];
  const int*   topk   = (const int*)d_in[4];
  const float* u      = (const float*)d_in[5];
  const int T  = in_sizes[1];
  const int V  = in_sizes[0] / T;
  const int NL = (out_size / T - 4) / 2;   // num_logprobs (=20): out = T + 2*T*(NL+1) + T
  sampler_kernel<<<T, TPB, 0, stream>>>(logits, temp, minp, topp, topk, u,
                                        (float*)d_out, T, V, NL);
}

// Round 2
// 303.327 us; speedup vs baseline: 1.4033x; 1.4033x over previous
//
#include <hip/hip_runtime.h>
#include <math.h>

#define TPB 1024
#define NW (TPB/64)
#define NBINS 512
#define CAP 2048
#define NSEL 64

typedef unsigned long long u64t;

// order-preserving key: descending by value (ascending uint key), ties -> ascending idx
__device__ __forceinline__ unsigned int fkeyDesc(float v) {
  unsigned int b = __float_as_uint(v);
  unsigned int o = (b & 0x80000000u) ? ~b : (b | 0x80000000u);
  return ~o;
}
__device__ __forceinline__ float fkeyInv(unsigned int kd) {
  unsigned int o = ~kd;
  unsigned int b = (o & 0x80000000u) ? (o & 0x7fffffffu) : ~o;
  return __uint_as_float(b);
}

__device__ void bitonicSortN(u64t* keys, int n) {
  for (unsigned int k = 2; k <= (unsigned int)n; k <<= 1) {
    for (unsigned int j = k >> 1; j > 0; j >>= 1) {
      __syncthreads();
      for (unsigned int i = threadIdx.x; i < (unsigned int)n; i += TPB) {
        unsigned int ixj = i ^ j;
        if (ixj > i) {
          u64t a = keys[i], b = keys[ixj];
          bool up = ((i & k) == 0);
          if ((a > b) == up) { keys[i] = b; keys[ixj] = a; }
        }
      }
    }
  }
  __syncthreads();
}

__device__ __forceinline__ float blockSumF(float v, float* sred) {
  #pragma unroll
  for (int o = 32; o > 0; o >>= 1) v += __shfl_down(v, o, 64);
  int wid = threadIdx.x >> 6, lane = threadIdx.x & 63;
  __syncthreads();
  if (lane == 0) sred[wid] = v;
  __syncthreads();
  if (threadIdx.x == 0) {
    float r = sred[0];
    for (int w = 1; w < NW; ++w) r += sred[w];
    sred[0] = r;
  }
  __syncthreads();
  float r = sred[0];
  __syncthreads();
  return r;
}

__device__ __forceinline__ int blockSumI(int v, int* sred) {
  #pragma unroll
  for (int o = 32; o > 0; o >>= 1) v += __shfl_down(v, o, 64);
  int wid = threadIdx.x >> 6, lane = threadIdx.x & 63;
  __syncthreads();
  if (lane == 0) sred[wid] = v;
  __syncthreads();
  if (threadIdx.x == 0) {
    int r = sred[0];
    for (int w = 1; w < NW; ++w) r += sred[w];
    sred[0] = r;
  }
  __syncthreads();
  int r = sred[0];
  __syncthreads();
  return r;
}

// max with tie -> smallest index
__device__ __forceinline__ void blockArgMaxF(float& v, int& idx, float* sredf, int* sredi) {
  #pragma unroll
  for (int o = 32; o > 0; o >>= 1) {
    float v2 = __shfl_down(v, o, 64);
    int  i2 = __shfl_down(idx, o, 64);
    if (v2 > v || (v2 == v && i2 < idx)) { v = v2; idx = i2; }
  }
  int wid = threadIdx.x >> 6, lane = threadIdx.x & 63;
  __syncthreads();
  if (lane == 0) { sredf[wid] = v; sredi[wid] = idx; }
  __syncthreads();
  if (threadIdx.x == 0) {
    float bv = sredf[0]; int bi = sredi[0];
    for (int w = 1; w < NW; ++w) {
      float v2 = sredf[w]; int i2 = sredi[w];
      if (v2 > bv || (v2 == bv && i2 < bi)) { bv = v2; bi = i2; }
    }
    sredf[0] = bv; sredi[0] = bi;
  }
  __syncthreads();
  v = sredf[0]; idx = sredi[0];
  __syncthreads();
}

__global__ __launch_bounds__(TPB) void sampler_kernel(
    const float* __restrict__ logits,
    const float* __restrict__ temp_arr,
    const float* __restrict__ minp_arr,
    const float* __restrict__ topp_arr,
    const int*   __restrict__ topk_arr,
    const float* __restrict__ u_arr,
    float* __restrict__ out,
    int T, int V, int NL)
{
  __shared__ u64t keyA[CAP];
  __shared__ u64t keyB[CAP];
  __shared__ float pvals[CAP];
  __shared__ int   cnthist[NBINS];
  __shared__ u64t  masshist[NBINS];
  __shared__ float sredF[NW];
  __shared__ int   sredI[NW];
  __shared__ float sh_thresh, sh_toklp, sh_Rm, sh_Roff;
  __shared__ double sh_seedD, sh_seedBase;
  __shared__ int sh_B64, sh_Bp, sh_cnt, sh_state;

  const int row = blockIdx.x;
  const int tid = threadIdx.x;
  const float* x  = logits + (size_t)row * V;
  const float* uu = u_arr  + (size_t)row * V;
  const float temp = temp_arr[row];
  const float minp = minp_arr[row];
  const float topp = topp_arr[row];
  const int   topk = topk_arr[row];
  const bool greedy = (temp < 1e-5f);
  const float st = greedy ? 1.0f : temp;
  const int V4 = V >> 2;
  const float4* x4 = (const float4*)x;

  // ===== P1: max + argmax of raw logits =====
  float m0; int gidx;
  {
    float lm = -INFINITY; int lidx = 0x7fffffff;
    for (int i4 = tid; i4 < V4; i4 += TPB) {
      float4 v = x4[i4]; int b = i4 << 2;
      if (v.x > lm) { lm = v.x; lidx = b; }
      if (v.y > lm) { lm = v.y; lidx = b + 1; }
      if (v.z > lm) { lm = v.z; lidx = b + 2; }
      if (v.w > lm) { lm = v.w; lidx = b + 3; }
    }
    for (int i = (V4 << 2) + tid; i < V; i += TPB) {
      float v = x[i]; if (v > lm) { lm = v; lidx = i; }
    }
    blockArgMaxF(lm, lidx, sredF, sredI);
    m0 = lm; gidx = lidx;
  }
  const float ml = m0 / st;

  // ===== P2: sums (S0, S) fused with restricted count-histogram =====
  float Rcur = 2.0f;
  float binScale = (float)NBINS / Rcur;
  for (int b = tid; b < NBINS; b += TPB) cnthist[b] = 0;
  __syncthreads();
  float S0, S;
  {
    float s0p = 0.f, slp = 0.f;
    auto histAdd = [&](float vv) {
      float fb = (m0 - vv) * binScale;
      if (fb < (float)NBINS) atomicAdd(&cnthist[(int)fb], 1);
    };
    if (!greedy) {
      for (int i4 = tid; i4 < V4; i4 += TPB) {
        float4 v = x4[i4];
        s0p += expf(v.x - m0) + expf(v.y - m0) + expf(v.z - m0) + expf(v.w - m0);
        slp += expf(v.x / st - ml) + expf(v.y / st - ml) + expf(v.z / st - ml) + expf(v.w / st - ml);
        histAdd(v.x); histAdd(v.y); histAdd(v.z); histAdd(v.w);
      }
      for (int i = (V4 << 2) + tid; i < V; i += TPB) {
        float v = x[i]; s0p += expf(v - m0); slp += expf(v / st - ml); histAdd(v);
      }
    } else {
      for (int i4 = tid; i4 < V4; i4 += TPB) {
        float4 v = x4[i4];
        s0p += expf(v.x - m0) + expf(v.y - m0) + expf(v.z - m0) + expf(v.w - m0);
        histAdd(v.x); histAdd(v.y); histAdd(v.z); histAdd(v.w);
      }
      for (int i = (V4 << 2) + tid; i < V; i += TPB) {
        float v = x[i]; s0p += expf(v - m0); histAdd(v);
      }
    }
    S0 = blockSumF(s0p, sredF);
    S = greedy ? S0 : blockSumF(slp, sredF);
  }

  // ===== find B64 (bin boundary holding >= need top candidates), retry rare =====
  int need = NSEL;
  if (topk > need) need = topk;
  if (need > CAP / 2) need = CAP / 2;
  if (need > V) need = V;
  int B64;
  for (int attempt = 0; ; ++attempt) {
    __syncthreads();
    if (tid == 0) {
      long long cum = 0; int b64 = -1; long long c64 = 0;
      for (int b = 0; b < NBINS; ++b) {
        cum += cnthist[b];
        if (cum >= need) { b64 = b; c64 = cum; break; }
      }
      int state;
      if (b64 >= 0 && c64 <= CAP) state = 1;
      else if (b64 < 0) state = 0;        // widen
      else state = 2;                     // zoom
      if (attempt >= 3 && state != 1) { state = 1; if (b64 < 0) b64 = NBINS - 1; }
      sh_state = state; sh_B64 = b64;
    }
    __syncthreads();
    if (sh_state == 1) { B64 = sh_B64; break; }
    Rcur = (sh_state == 0) ? Rcur * 8.0f : Rcur * 0.125f;
    binScale = (float)NBINS / Rcur;
    __syncthreads();
    for (int b = tid; b < NBINS; b += TPB) cnthist[b] = 0;
    __syncthreads();
    auto histAdd2 = [&](float vv) {
      float fb = (m0 - vv) * binScale;
      if (fb < (float)NBINS) atomicAdd(&cnthist[(int)fb], 1);
    };
    for (int i4 = tid; i4 < V4; i4 += TPB) {
      float4 v = x4[i4];
      histAdd2(v.x); histAdd2(v.y); histAdd2(v.z); histAdd2(v.w);
    }
    for (int i = (V4 << 2) + tid; i < V; i += TPB) histAdd2(x[i]);
  }

  const float logS0 = logf(S0);
  const float rhs = minp * (1.0f / S);          // min_p * max_p as in reference
  const float rhsS = rhs * S;
  const float rhsHi = rhsS * (1.0f + 1e-6f);
  const float rhsLo = rhsS * (1.0f - 1e-6f);
  auto keepTest = [&](float e) -> bool {        // exact division only in ambiguous band
    if (e > rhsHi) return true;
    if (e < rhsLo) return false;
    return (e / S) >= rhs;
  };
  const bool needMass = (!greedy && topk <= 0);
  const float scaleM0 = (float)NBINS / 16.0f;

  // ===== PB: collect candidates + Sp/ck + (deep rows) mass hist =====
  for (int b = tid; b < NBINS; b += TPB) { cnthist[b] = 0; masshist[b] = 0ull; }
  if (tid == 0) { sh_cnt = 0; sh_Rm = 16.0f; sh_Roff = 0.0f; sh_seedBase = 0.0; }
  __syncthreads();
  float Sp; int ck;
  {
    float spp = 0.f; int ckp = 0;
    auto bodyB = [&](float vv, int gi) {
      float fb = (m0 - vv) * binScale;
      if (fb < (float)NBINS && (int)fb <= B64) {
        int pos = atomicAdd(&sh_cnt, 1);
        if (pos < CAP) keyA[pos] = ((u64t)fkeyDesc(vv) << 32) | (unsigned int)gi;
      }
      if (!greedy) {
        float l = vv / st;
        float e = expf(l - ml);
        if (keepTest(e)) {
          spp += e; ckp++;
          if (needMass) {
            float fm = (m0 - vv) * scaleM0;
            if (fm < (float)NBINS) {
              int bm = (int)fm;
              atomicAdd(&masshist[bm], (u64t)((double)e * 4294967296.0)); // fixed point: deterministic
              atomicAdd(&cnthist[bm], 1);
            }
          }
        }
      }
    };
    for (int i4 = tid; i4 < V4; i4 += TPB) {
      float4 v = x4[i4]; int b = i4 << 2;
      bodyB(v.x, b); bodyB(v.y, b + 1); bodyB(v.z, b + 2); bodyB(v.w, b + 3);
    }
    for (int i = (V4 << 2) + tid; i < V; i += TPB) bodyB(x[i], i);
    Sp = blockSumF(spp, sredF);
    ck = blockSumI(ckp, sredI);
  }
  int Cact = sh_cnt; if (Cact > CAP) Cact = CAP;

  // ===== sort candidates by x (keyA) and by lp (keyB), adaptive size =====
  int n = 128; while (n < Cact) n <<= 1;
  for (int i = Cact + tid; i < n; i += TPB) keyA[i] = ~0ull;
  __syncthreads();
  bitonicSortN(keyA, n);
  for (int j = tid; j < n; j += TPB) {
    if (j < Cact) {
      u64t ka = keyA[j];
      float xv = fkeyInv((unsigned int)(ka >> 32));
      float lp = (xv - m0) - logS0;
      keyB[j] = ((u64t)fkeyDesc(lp) << 32) | (ka & 0xffffffffu);
    } else keyB[j] = ~0ull;
  }
  bitonicSortN(keyB, n);

  // ===== sampling =====
  int sampled;
  if (greedy) {
    sampled = gidx;
  } else if (topk > 0) {
    // top-k/top-p threshold from sorted candidates (serial, <=63 iters)
    if (tid == 0) {
      int k = topk; if (k > V) k = V; if (k > CAP) k = CAP;
      int jp = 0; float cum = 0.f;
      for (int j = 0; j < k; ++j) {
        float pj = 0.f;
        if (j < ck && j < Cact) {
          float xv = fkeyInv((unsigned int)(keyA[j] >> 32));
          pj = expf(xv / st - ml) / Sp;
        }
        cum += pj;
        float ex = cum - pj;               // emulate ref's (cumsum - probs)
        if (ex < topp) jp = j;
      }
      float thr;
      if (jp < ck && jp < Cact) {
        float xv = fkeyInv((unsigned int)(keyA[jp] >> 32));
        thr = xv / st;
      } else thr = -INFINITY;
      sh_thresh = thr;
    }
    __syncthreads();
    const float thr = sh_thresh;
    // Gumbel argmax over candidates only (kept set is subset of top-need by x)
    float bm = -INFINITY; int bi = 0x7fffffff;
    for (int j = tid; j < Cact; j += TPB) {
      u64t ka = keyA[j];
      float xv = fkeyInv((unsigned int)(ka >> 32));
      int gi = (int)(ka & 0xffffffffu);
      float l = xv / st;
      float e = expf(l - ml);
      if (keepTest(e) && l >= thr) {
        float uv = uu[gi];
        float g = -logf(-logf(uv));
        float val = l + g;
        if (val > bm || (val == bm && gi < bi)) { bm = val; bi = gi; }
      }
    }
    blockArgMaxF(bm, bi, sredF, sredI);
    sampled = bi;
  } else {
    // ===== deep path (top_k==0): locate top-p crossing via mass hist =====
    for (int attempt = 0; ; ++attempt) {
      __syncthreads();
      if (tid == 0) {
        float Rm = sh_Rm, Roff = sh_Roff;
        double TP = (double)topp * (double)Sp;
        double cm = sh_seedBase; int bp = -1; double seed = sh_seedBase; int cbp = 0;
        for (int b = 0; b < NBINS; ++b) {
          u64t mh = masshist[b];
          if (mh > 0ull && cm < TP) { bp = b; seed = cm; cbp = cnthist[b]; }
          cm += (double)mh * (1.0 / 4294967296.0);
        }
        int state = 1;
        if (attempt < 3) {
          if (cm < TP && Roff == 0.0f) {       // crossing beyond window -> widen
            state = 0; sh_Rm = Rm * 8.0f;
          } else if (bp >= 0 && cbp > CAP) {   // crossing bin too big -> refine
            state = 2;
            float bw = Rm / (float)NBINS;
            sh_Roff = Roff + (float)bp * bw;
            sh_Rm = bw;
            sh_seedBase = seed;
          }
        }
        if (bp < 0) { bp = 0; seed = sh_seedBase; }
        sh_Bp = bp; sh_seedD = seed; sh_state = state;
      }
      __syncthreads();
      if (sh_state == 1) break;
      float Rm = sh_Rm, Roff = sh_Roff;
      float sM = (float)NBINS / Rm;
      for (int b = tid; b < NBINS; b += TPB) { cnthist[b] = 0; masshist[b] = 0ull; }
      __syncthreads();
      auto bodyM = [&](float vv) {
        float fm = ((m0 - vv) - Roff) * sM;
        if (fm >= 0.f && fm < (float)NBINS) {
          float l = vv / st;
          float e = expf(l - ml);
          if (keepTest(e)) {
            int bm = (int)fm;
            atomicAdd(&masshist[bm], (u64t)((double)e * 4294967296.0));
            atomicAdd(&cnthist[bm], 1);
          }
        }
      };
      for (int i4 = tid; i4 < V4; i4 += TPB) {
        float4 v = x4[i4]; bodyM(v.x); bodyM(v.y); bodyM(v.z); bodyM(v.w);
      }
      for (int i = (V4 << 2) + tid; i < V; i += TPB) bodyM(x[i]);
    }
    const int Bp = sh_Bp;
    const float RmF = sh_Rm, RoffF = sh_Roff;
    const float sM = (float)NBINS / RmF;
    // collect crossing bin (kept only), sort, sequential scan for pth
    if (tid == 0) sh_cnt = 0;
    __syncthreads();
    auto bodyC = [&](float vv, int gi) {
      float fm = ((m0 - vv) - RoffF) * sM;
      if (fm >= 0.f && fm < (float)NBINS && (int)fm == Bp) {
        float l = vv / st;
        float e = expf(l - ml);
        if (keepTest(e)) {
          int pos = atomicAdd(&sh_cnt, 1);
          if (pos < CAP) keyA[pos] = ((u64t)fkeyDesc(vv) << 32) | (unsigned int)gi;
        }
      }
    };
    for (int i4 = tid; i4 < V4; i4 += TPB) {
      float4 v = x4[i4]; int b = i4 << 2;
      bodyC(v.x, b); bodyC(v.y, b + 1); bodyC(v.z, b + 2); bodyC(v.w, b + 3);
    }
    for (int i = (V4 << 2) + tid; i < V; i += TPB) bodyC(x[i], i);
    __syncthreads();
    int C5 = sh_cnt; if (C5 > CAP) C5 = CAP;
    int n5 = 128; while (n5 < C5) n5 <<= 1;
    for (int i = C5 + tid; i < n5; i += TPB) keyA[i] = ~0ull;
    __syncthreads();
    bitonicSortN(keyA, n5);
    for (int j = tid; j < C5; j += TPB) {
      float xv = fkeyInv((unsigned int)(keyA[j] >> 32));
      pvals[j] = expf(xv / st - ml) / Sp;
    }
    __syncthreads();
    if (tid == 0) {
      float cum = (float)(sh_seedD / (double)Sp);
      float lastVal = fkeyInv((unsigned int)(keyA[0] >> 32));
      for (int j = 0; j < C5; ++j) {
        float pj = pvals[j];
        cum += pj;
        float ex = cum - pj;
        if (ex < topp) lastVal = fkeyInv((unsigned int)(keyA[j] >> 32));
      }
      sh_thresh = lastVal / st;
    }
    __syncthreads();
    // full Gumbel pass (kept set may be deep)
    const float thr = sh_thresh;
    const float4* u4 = (const float4*)uu;
    float bm = -INFINITY; int bi = 0x7fffffff;
    auto body6 = [&](float vv, float uv, int gi) {
      float l = vv / st;
      float e = expf(l - ml);
      if (keepTest(e) && l >= thr) {
        float g = -logf(-logf(uv));
        float val = l + g;
        if (val > bm || (val == bm && gi < bi)) { bm = val; bi = gi; }
      }
    };
    for (int i4 = tid; i4 < V4; i4 += TPB) {
      float4 v = x4[i4]; float4 w = u4[i4]; int b = i4 << 2;
      body6(v.x, w.x, b); body6(v.y, w.y, b + 1); body6(v.z, w.z, b + 2); body6(v.w, w.w, b + 3);
    }
    for (int i = (V4 << 2) + tid; i < V; i += TPB) body6(x[i], uu[i], i);
    blockArgMaxF(bm, bi, sredF, sredI);
    sampled = bi;
  }

  // ===== token logprob + rank =====
  if (tid == 0) sh_toklp = (x[sampled] - m0) - logS0;
  __syncthreads();
  const float toklp = sh_toklp;
  int rank;
  {
    int rc = 0;
    if (!needMass) {
      // all lp >= toklp elements are inside the candidate set
      for (int j = tid; j < Cact; j += TPB) {
        float xv = fkeyInv((unsigned int)(keyA[j] >> 32));
        float lp = (xv - m0) - logS0;
        if (lp >= toklp) rc++;
      }
    } else {
      auto body7 = [&](float vv) {
        float lp = (vv - m0) - logS0;
        if (lp >= toklp) rc++;
      };
      for (int i4 = tid; i4 < V4; i4 += TPB) {
        float4 v = x4[i4]; body7(v.x); body7(v.y); body7(v.z); body7(v.w);
      }
      for (int i = (V4 << 2) + tid; i < V; i += TPB) body7(x[i]);
    }
    rank = blockSumI(rc, sredI);
  }

  // ===== outputs (all float32 into concat buffer) =====
  float* o_samp = out;
  float* o_idx  = out + T;
  float* o_lps  = out + T + (size_t)T * (NL + 1);
  float* o_rank = out + T + (size_t)2 * T * (NL + 1);
  if (tid == 0) {
    o_samp[row] = (float)sampled;
    o_idx[(size_t)row * (NL + 1)] = (float)sampled;
    o_lps[(size_t)row * (NL + 1)] = toklp;
    o_rank[row] = (float)rank;
  }
  for (int j = tid; j < NL; j += TPB) {
    u64t kb = keyB[j];
    o_idx[(size_t)row * (NL + 1) + 1 + j] = (float)(unsigned int)(kb & 0xffffffffu);
    o_lps[(size_t)row * (NL + 1) + 1 + j] = fkeyInv((unsigned int)(kb >> 32));
  }
}

extern "C" void kernel_launch(void* const* d_in, const int* in_sizes, int n_in,
                              void* d_out, int out_size, void* d_ws, size_t ws_size,
                              hipStream_t stream) {
  const float* logits = (const float*)d_in[0];
  const float* temp   = (const float*)d_in[1];
  const float* minp   = (const float*)d_in[2];
  const float* topp   = (const float*)d_in[3];
  const int*   topk   = (const int*)d_in[4];
  const float* u      = (const float*)d_in[5];
  const int T  = in_sizes[1];
  const int V  = in_sizes[0] / T;
  const int NL = (out_size / T - 4) / 2;
  sampler_kernel<<<T, TPB, 0, stream>>>(logits, temp, minp, topp, topk, u,
                                        (float*)d_out, T, V, NL);
}